// Round 8
// baseline (187.474 us; speedup 1.0000x reference)
//
#include <hip/hip_runtime.h>

constexpr int N_OBJ = 4096, N_REG = 8192, D = 512, GW = 128, NE = 131072;

typedef __attribute__((ext_vector_type(8))) short short8;
typedef __attribute__((ext_vector_type(4))) float f32x4;
typedef __attribute__((ext_vector_type(2))) float f32x2;

__device__ inline short f2bf(float f) {
  unsigned u = __builtin_bit_cast(unsigned, f);
  unsigned r = (u + 0x7FFF + ((u >> 16) & 1)) >> 16;
  return (short)r;
}

// ---------- one-pass cast (features raw-fp8 + relu-bf16, combined weights bf16) + CSR ----------
__global__ __launch_bounds__(256) void cast_csr(
    const float* __restrict__ feat_reg, const float* __restrict__ feat_obj,
    const float* __restrict__ gw_r2o, const float* __restrict__ gw_o2r,
    const float* __restrict__ tw_r2o, const float* __restrict__ tw_o2r,
    const int* __restrict__ t_r2o, const int* __restrict__ t_o2r,
    unsigned char* __restrict__ raw_reg, short* __restrict__ relu_reg,
    unsigned char* __restrict__ raw_obj, short* __restrict__ relu_obj,
    short* __restrict__ Wreg, short* __restrict__ Wobj,
    short* __restrict__ btw_r2o, short* __restrict__ btw_o2r,
    int* __restrict__ off_r2o, int* __restrict__ off_o2r) {
  int i = blockIdx.x * 256 + threadIdx.x;
  if (i >= 1769472) {  // CSR tail
    i -= 1769472;
    const int* tgt; int* off; int t;
    if (i <= N_OBJ) { tgt = t_r2o; off = off_r2o; t = i; }
    else {
      i -= N_OBJ + 1;
      if (i > N_REG) return;
      tgt = t_o2r; off = off_o2r; t = i;
    }
    int lo = 0, hi = NE;
    while (lo < hi) {
      int mid = (lo + hi) >> 1;
      if (tgt[mid] < t) lo = mid + 1; else hi = mid;
    }
    off[t] = lo;
    return;
  }
  if (i < 1572864) {  // feature path: raw fp8 + relu bf16
    const float* src; unsigned char* draw; short* drelu; int j = i;
    if (j < 1048576) { src = feat_reg; draw = raw_reg; drelu = relu_reg; }
    else { j -= 1048576; src = feat_obj; draw = raw_obj; drelu = relu_obj; }
    float4 v = ((const float4*)src)[j];
    int p = __builtin_amdgcn_cvt_pk_fp8_f32(v.x, v.y, 0, false);
    p = __builtin_amdgcn_cvt_pk_fp8_f32(v.z, v.w, p, true);
    ((unsigned*)draw)[j] = (unsigned)p;
    ((short4*)drelu)[j] = make_short4(f2bf(fmaxf(v.x, 0.f)), f2bf(fmaxf(v.y, 0.f)),
                                      f2bf(fmaxf(v.z, 0.f)), f2bf(fmaxf(v.w, 0.f)));
    return;
  }
  i -= 1572864;
  const float* src; short* dst; int di;
  if (i < 32768) {            // Wreg[j<128]=gw_r2o[j][:512]; [j>=128]=gw_o2r[j-128][512:]
    int row = i >> 7, c4 = i & 127;
    src = (row < 128) ? gw_r2o + (size_t)row * 1024 + c4 * 4
                      : gw_o2r + (size_t)(row - 128) * 1024 + 512 + c4 * 4;
    dst = Wreg; di = i;
  } else if (i < 65536) {     // Wobj[j<128]=gw_r2o[j][512:]; [j>=128]=gw_o2r[j-128][:512]
    int k = i - 32768, row = k >> 7, c4 = k & 127;
    src = (row < 128) ? gw_r2o + (size_t)row * 1024 + 512 + c4 * 4
                      : gw_o2r + (size_t)(row - 128) * 1024 + c4 * 4;
    dst = Wobj; di = k;
  } else if (i < 131072) { di = i - 65536; src = tw_r2o + (size_t)di * 4; dst = btw_r2o; }
  else                   { di = i - 131072; src = tw_o2r + (size_t)di * 4; dst = btw_o2r; }
  float4 v = *(const float4*)src;
  ((short4*)dst)[di] = make_short4(f2bf(v.x), f2bf(v.y), f2bf(v.z), f2bf(v.w));
}

// ---------- paired bf16 MFMA GEMM, double-buffered stage-ahead ----------
// EPI: fp32 C = acc + res + bias. !EPI: fp8 C (projection outputs).
struct GemmPair {
  const short* A[2]; const short* B[2];
  const float* res[2]; const float* bias[2];
  void* C[2];
  int nb0;   // #blocks of problem 0
  int nxb;   // x-blocks (N/BN)
  int ldc;
};

template<bool EPI, int BN>
__global__ __launch_bounds__(256) void gemm_pair(GemmPair gp) {
  constexpr int NF = BN / 32;           // B fragments per wave (2 N-waves)
  __shared__ short As[2][128 * 32];
  __shared__ short Bs[2][BN * 32];
  int b = blockIdx.x;
  const int pi = (b >= gp.nb0) ? 1 : 0;
  if (pi) b -= gp.nb0;
  const int bx = b % gp.nxb, by = b / gp.nxb;
  const short* __restrict__ A = gp.A[pi];
  const short* __restrict__ B = gp.B[pi];
  const int ldc = gp.ldc;
  const int tid = threadIdx.x;
  const int lane = tid & 63, w = tid >> 6;
  const int m0 = by * 128, n0 = bx * BN;
  const int wm = (w >> 1) * 64, wn = (w & 1) * (BN / 2);
  const int sr = lane >> 2, sc = (lane & 3) * 8;
  const int fr = lane & 15, fk = (lane >> 4) * 8;

  f32x4 acc[4][NF];
#pragma unroll
  for (int i = 0; i < 4; ++i)
#pragma unroll
    for (int j = 0; j < NF; ++j) acc[i][j] = (f32x4){0.f, 0.f, 0.f, 0.f};

  auto stage = [&](int buf, int k0) {
#pragma unroll
    for (int h = 0; h < 2; ++h) {
      int rg = w * 32 + h * 16;
      const short* ga = A + (size_t)(m0 + rg + sr) * 512 + k0 + sc;
      __builtin_amdgcn_global_load_lds(
          (const __attribute__((address_space(1))) void*)ga,
          (__attribute__((address_space(3))) void*)&As[buf][rg * 32], 16, 0, 0);
    }
#pragma unroll
    for (int h = 0; h < BN / 64; ++h) {
      int rg = w * (BN / 4) + h * 16;
      const short* gb = B + (size_t)(n0 + rg + sr) * 512 + k0 + sc;
      __builtin_amdgcn_global_load_lds(
          (const __attribute__((address_space(1))) void*)gb,
          (__attribute__((address_space(3))) void*)&Bs[buf][rg * 32], 16, 0, 0);
    }
  };
  auto compute = [&](int buf) {
    short8 a[4], bb[NF];
#pragma unroll
    for (int i = 0; i < 4; ++i)
      a[i] = *(const short8*)&As[buf][(wm + i * 16 + fr) * 32 + fk];
#pragma unroll
    for (int j = 0; j < NF; ++j)
      bb[j] = *(const short8*)&Bs[buf][(wn + j * 16 + fr) * 32 + fk];
#pragma unroll
    for (int i = 0; i < 4; ++i)
#pragma unroll
      for (int j = 0; j < NF; ++j)
        acc[i][j] = __builtin_amdgcn_mfma_f32_16x16x32_bf16(a[i], bb[j], acc[i][j], 0, 0, 0);
  };

  stage(0, 0);
  __syncthreads();                      // drains vmcnt (compiler) -> buf0 ready
  int cur = 0;
  for (int k0 = 0; k0 < 512 - 32; k0 += 32) {
    stage(cur ^ 1, k0 + 32);            // prefetch next K-tile (overlaps MFMA below)
    compute(cur);
    __syncthreads();                    // one barrier per K-step: drains vmcnt+lgkm
    cur ^= 1;
  }
  compute(cur);

  if (EPI) {
    float* C = (float*)gp.C[pi];
    const float* res = gp.res[pi];
    const float* bias = gp.bias[pi];
#pragma unroll
    for (int i = 0; i < 4; ++i)
#pragma unroll
      for (int j = 0; j < NF; ++j) {
        int n = n0 + wn + j * 16 + fr;
#pragma unroll
        for (int r = 0; r < 4; ++r) {
          int m = m0 + wm + i * 16 + (lane >> 4) * 4 + r;
          C[(size_t)m * ldc + n] = acc[i][j][r] + res[(size_t)m * ldc + n] + bias[n];
        }
      }
  } else {
    unsigned char* C = (unsigned char*)gp.C[pi];
#pragma unroll
    for (int i = 0; i < 4; ++i)
#pragma unroll
      for (int j = 0; j < NF; ++j) {
        int n = n0 + wn + j * 16 + fr;
#pragma unroll
        for (int r = 0; r < 4; ++r) {
          int m = m0 + wm + i * 16 + (lane >> 4) * 4 + r;
          int pk = __builtin_amdgcn_cvt_pk_fp8_f32(acc[i][j][r], acc[i][j][r], 0, false);
          C[(size_t)m * ldc + n] = (unsigned char)(pk & 0xFF);
        }
      }
  }
}

// ---------- FUSED gate + segment-mean, both directions, fp8 gathers, unroll-2 ----------
__global__ __launch_bounds__(256) void fused_msg(
    const unsigned char* __restrict__ Preg, const unsigned char* __restrict__ Pobj,
    const unsigned char* __restrict__ raw_reg, const unsigned char* __restrict__ raw_obj,
    const int* __restrict__ r2o_src, const int* __restrict__ o2r_src,
    const int* __restrict__ off_r2o, const int* __restrict__ off_o2r,
    const float* __restrict__ gb_r2o, const float* __restrict__ gb_o2r,
    short* __restrict__ m_obj, short* __restrict__ m_reg) {
  __shared__ float red[4][512];
  int t = blockIdx.x;
  const unsigned char *PA, *PB, *feat; const int *src, *off; const float* gb;
  short* mo; int po;
  if (t < N_OBJ) {
    PA = Preg; PB = Pobj; feat = raw_reg; src = r2o_src; off = off_r2o;
    gb = gb_r2o; mo = m_obj; po = 0;
  } else {
    t -= N_OBJ;
    PA = Pobj; PB = Preg; feat = raw_obj; src = o2r_src; off = off_o2r;
    gb = gb_o2r; mo = m_reg; po = 128;
  }
  const int tid = threadIdx.x, lane = tid & 63, w = tid >> 6;
  const int hw = lane >> 5, l = lane & 31;
  const int e0 = off[t], e1 = off[t + 1];
  // per-target constants: PB[t] row (fp8) + gate bias, 4 elems/lane
  unsigned pbu = *(const unsigned*)&PB[(size_t)t * 256 + po + l * 4];
  f32x2 pb01 = __builtin_amdgcn_cvt_pk_f32_fp8((int)pbu, false);
  f32x2 pb23 = __builtin_amdgcn_cvt_pk_f32_fp8((int)pbu, true);
  float4 gbv = *(const float4*)&gb[l * 4];
  const float c0 = pb01.x + gbv.x, c1 = pb01.y + gbv.y;
  const float c2 = pb23.x + gbv.z, c3 = pb23.y + gbv.w;
  float acc[16] = {};

  auto sig4 = [&](unsigned pau) -> float {
    f32x2 a01 = __builtin_amdgcn_cvt_pk_f32_fp8((int)pau, false);
    f32x2 a23 = __builtin_amdgcn_cvt_pk_f32_fp8((int)pau, true);
    return __builtin_amdgcn_rcpf(1.f + __expf(-(a01.x + c0)))
         + __builtin_amdgcn_rcpf(1.f + __expf(-(a01.y + c1)))
         + __builtin_amdgcn_rcpf(1.f + __expf(-(a23.x + c2)))
         + __builtin_amdgcn_rcpf(1.f + __expf(-(a23.y + c3)));
  };
  auto accum = [&](uint4 fv, float gs) {
    f32x2 f0 = __builtin_amdgcn_cvt_pk_f32_fp8((int)fv.x, false);
    f32x2 f1 = __builtin_amdgcn_cvt_pk_f32_fp8((int)fv.x, true);
    f32x2 f2 = __builtin_amdgcn_cvt_pk_f32_fp8((int)fv.y, false);
    f32x2 f3 = __builtin_amdgcn_cvt_pk_f32_fp8((int)fv.y, true);
    f32x2 f4 = __builtin_amdgcn_cvt_pk_f32_fp8((int)fv.z, false);
    f32x2 f5 = __builtin_amdgcn_cvt_pk_f32_fp8((int)fv.z, true);
    f32x2 f6 = __builtin_amdgcn_cvt_pk_f32_fp8((int)fv.w, false);
    f32x2 f7 = __builtin_amdgcn_cvt_pk_f32_fp8((int)fv.w, true);
    acc[0]  += f0.x * gs; acc[1]  += f0.y * gs;
    acc[2]  += f1.x * gs; acc[3]  += f1.y * gs;
    acc[4]  += f2.x * gs; acc[5]  += f2.y * gs;
    acc[6]  += f3.x * gs; acc[7]  += f3.y * gs;
    acc[8]  += f4.x * gs; acc[9]  += f4.y * gs;
    acc[10] += f5.x * gs; acc[11] += f5.y * gs;
    acc[12] += f6.x * gs; acc[13] += f6.y * gs;
    acc[14] += f7.x * gs; acc[15] += f7.y * gs;
  };

  int e = e0 + w * 2 + hw;
  for (; e + 8 < e1; e += 16) {   // two edges in flight per half-wave
    int s0 = src[e], s1 = src[e + 8];
    unsigned pau0 = *(const unsigned*)&PA[(size_t)s0 * 256 + po + l * 4];
    uint4 fv0 = *(const uint4*)&feat[(size_t)s0 * 512 + l * 16];
    unsigned pau1 = *(const unsigned*)&PA[(size_t)s1 * 256 + po + l * 4];
    uint4 fv1 = *(const uint4*)&feat[(size_t)s1 * 512 + l * 16];
    float gs0 = sig4(pau0), gs1 = sig4(pau1);
#pragma unroll
    for (int msk = 16; msk >= 1; msk >>= 1) {
      gs0 += __shfl_xor(gs0, msk, 64);
      gs1 += __shfl_xor(gs1, msk, 64);
    }
    accum(fv0, gs0);
    accum(fv1, gs1);
  }
  for (; e < e1; e += 8) {        // tail (at most one per half-wave)
    int s = src[e];
    unsigned pau = *(const unsigned*)&PA[(size_t)s * 256 + po + l * 4];
    uint4 fv = *(const uint4*)&feat[(size_t)s * 512 + l * 16];
    float gs = sig4(pau);
#pragma unroll
    for (int msk = 16; msk >= 1; msk >>= 1) gs += __shfl_xor(gs, msk, 64);
    accum(fv, gs);
  }
  // merge the two half-waves (lane l <-> l+32), then half 0 writes LDS
#pragma unroll
  for (int jj = 0; jj < 16; ++jj) acc[jj] += __shfl_xor(acc[jj], 32, 64);
  if (hw == 0) {
#pragma unroll
    for (int q = 0; q < 4; ++q)
      *(float4*)&red[w][l * 16 + q * 4] =
          (float4){acc[q * 4], acc[q * 4 + 1], acc[q * 4 + 2], acc[q * 4 + 3]};
  }
  __syncthreads();
  const float inv = (1.0f / 128.0f) / fmaxf((float)(e1 - e0), 1.0f);
  const int d = tid * 2;
  float s0 = red[0][d] + red[1][d] + red[2][d] + red[3][d];
  float s1 = red[0][d + 1] + red[1][d + 1] + red[2][d + 1] + red[3][d + 1];
  short2 o;
  o.x = f2bf(fmaxf(s0 * inv, 0.f));
  o.y = f2bf(fmaxf(s1 * inv, 0.f));
  *(short2*)(mo + (size_t)t * 512 + d) = o;
}

extern "C" void kernel_launch(void* const* d_in, const int* in_sizes, int n_in,
                              void* d_out, int out_size, void* d_ws, size_t ws_size,
                              hipStream_t stream) {
  const float* feat_obj = (const float*)d_in[0];
  const float* feat_reg = (const float*)d_in[1];
  const int*   r2o_tgt  = (const int*)d_in[2];
  const int*   r2o_src  = (const int*)d_in[3];
  const int*   o2r_tgt  = (const int*)d_in[4];
  const int*   o2r_src  = (const int*)d_in[5];
  const float* gw_r2o   = (const float*)d_in[6];
  const float* gb_r2o   = (const float*)d_in[7];
  const float* gw_o2r   = (const float*)d_in[8];
  const float* gb_o2r   = (const float*)d_in[9];
  const float* tw_r2o   = (const float*)d_in[10];
  const float* tb_r2o   = (const float*)d_in[11];
  const float* tw_o2r   = (const float*)d_in[12];
  const float* tb_o2r   = (const float*)d_in[13];
  float* out_obj = (float*)d_out;
  float* out_reg = out_obj + (size_t)N_OBJ * D;

  size_t cur = 0;
  auto alloc = [&](size_t bytes) -> void* {
    cur = (cur + 255) & ~(size_t)255;
    void* p = (char*)d_ws + cur;
    cur += bytes;
    return p;
  };
  int*   off_r2o = (int*)alloc((N_OBJ + 1) * sizeof(int));
  int*   off_o2r = (int*)alloc((N_REG + 1) * sizeof(int));
  unsigned char* raw_reg = (unsigned char*)alloc((size_t)N_REG * D);   // fp8
  unsigned char* raw_obj = (unsigned char*)alloc((size_t)N_OBJ * D);   // fp8
  short* relu_reg= (short*)alloc((size_t)N_REG * D * 2);
  short* relu_obj= (short*)alloc((size_t)N_OBJ * D * 2);
  short* Wreg    = (short*)alloc((size_t)256 * D * 2);
  short* Wobj    = (short*)alloc((size_t)256 * D * 2);
  short* btw_r2o = (short*)alloc((size_t)D * D * 2);
  short* btw_o2r = (short*)alloc((size_t)D * D * 2);
  unsigned char* Preg = (unsigned char*)alloc((size_t)N_REG * 256);    // fp8
  unsigned char* Pobj = (unsigned char*)alloc((size_t)N_OBJ * 256);    // fp8
  short* m_obj   = (short*)alloc((size_t)N_OBJ * D * 2);
  short* m_reg   = (short*)alloc((size_t)N_REG * D * 2);

  cast_csr<<<6961, 256, 0, stream>>>(feat_reg, feat_obj, gw_r2o, gw_o2r, tw_r2o, tw_o2r,
                                     r2o_tgt, o2r_tgt,
                                     raw_reg, relu_reg, raw_obj, relu_obj,
                                     Wreg, Wobj, btw_r2o, btw_o2r, off_r2o, off_o2r);

  GemmPair proj;
  proj.A[0] = relu_reg; proj.B[0] = Wreg; proj.C[0] = Preg;
  proj.A[1] = relu_obj; proj.B[1] = Wobj; proj.C[1] = Pobj;
  proj.res[0] = proj.res[1] = nullptr; proj.bias[0] = proj.bias[1] = nullptr;
  proj.nb0 = 4 * (N_REG / 128); proj.nxb = 4; proj.ldc = 256;       // BN=64
  gemm_pair<false, 64><<<384, 256, 0, stream>>>(proj);

  fused_msg<<<N_OBJ + N_REG, 256, 0, stream>>>(Preg, Pobj, raw_reg, raw_obj,
                                               r2o_src, o2r_src, off_r2o, off_o2r,
                                               gb_r2o, gb_o2r, m_obj, m_reg);

  GemmPair tr;
  tr.A[0] = m_reg; tr.B[0] = btw_o2r; tr.res[0] = feat_reg; tr.bias[0] = tb_o2r; tr.C[0] = out_reg;
  tr.A[1] = m_obj; tr.B[1] = btw_r2o; tr.res[1] = feat_obj; tr.bias[1] = tb_r2o; tr.C[1] = out_obj;
  tr.nb0 = 4 * (N_REG / 128); tr.nxb = 4; tr.ldc = D;               // BN=128
  gemm_pair<true, 128><<<384, 256, 0, stream>>>(tr);
}